// Round 4
// baseline (8154.375 us; speedup 1.0000x reference)
//
#include <hip/hip_runtime.h>
#include <hip/hip_fp16.h>

#define T_LEN 1024
#define B_SZ  32
#define D_IN  768
#define H_SZ  768
#define G4    3072   // 4*H
#define LDA   40     // xg_gemm: padded LDS row stride (bf16) for 32-wide K tiles
#define HPAD  776    // lstm_rec: padded row stride (bf16): uniform 8-way b128 = floor

typedef __attribute__((ext_vector_type(8))) short short8;  // 8 bf16 (4 VGPRs)
typedef __attribute__((ext_vector_type(4))) float f32x4;   // MFMA 16x16 C/D frag
typedef __attribute__((ext_vector_type(4))) unsigned u32x4; // asm-friendly 16B

// ---------------------------------------------------------------------------
// Chunk exchange buffer: [parity][domain][producer r][chunk 0..31] x 16 B.
// chunk = {tag, v0, v1, v2}, v = (bf16hi<<16)|bf16lo of one h value (exactly
// the precision the split-bf16 MFMA consumes). Tag+data in ONE 16-B store ->
// publish and data delivery are a single L3 hop. 256 KB: L3-resident.
// ---------------------------------------------------------------------------
__device__ u32x4 chunk_glb[2 * 2 * 128 * 32];

__global__ void zero_chunks() {
    u32x4 z; z.x = 0u; z.y = 0u; z.z = 0u; z.w = 0u;
    chunk_glb[blockIdx.x * 256 + threadIdx.x] = z;
}

// bitwise fp32 -> bf16 hi/lo split (exact residual; 3-term MFMA error ~2^-16 rel)
__device__ __forceinline__ void split2(float x0, float x1, unsigned& hp, unsigned& lp)
{
    const unsigned u0 = __float_as_uint(x0);
    const unsigned u1 = __float_as_uint(x1);
    const unsigned h0 = u0 & 0xffff0000u, h1 = u1 & 0xffff0000u;
    hp = (h0 >> 16) | h1;
    const float l0 = x0 - __uint_as_float(h0);
    const float l1 = x1 - __uint_as_float(h1);
    lp = (__float_as_uint(l0) >> 16) | (__float_as_uint(l1) & 0xffff0000u);
}

// ---------------------------------------------------------------------------
// Phase A: xg = hidden @ W_ih^T + biases. Split-bf16 3-term MFMA GEMM
// (verified R1/R2: ~0.36 ms, absmax unchanged). Unchanged.
// ---------------------------------------------------------------------------
__global__ __launch_bounds__(256, 2)
void xg_gemm(const float* __restrict__ hidden, const float* __restrict__ W_ih,
             const float* __restrict__ b_ih, const float* __restrict__ b_hh,
             __half* __restrict__ xg)
{
    __shared__ unsigned short Ah[128 * LDA];
    __shared__ unsigned short Al[128 * LDA];
    __shared__ unsigned short Bh[128 * LDA];
    __shared__ unsigned short Bl[128 * LDA];

    const int tid = threadIdx.x;
    const int n0 = blockIdx.x * 128;
    const int m0 = blockIdx.y * 128;

    const int srow = tid >> 1;
    const int skh  = (tid & 1) * 16;
    const int m = m0 + srow;
    const float* arow = hidden + ((size_t)(m & 31) * T_LEN + (m >> 5)) * D_IN;
    const float* brow = W_ih + (size_t)(n0 + srow) * D_IN;

    const int lane = tid & 63;
    const int wid  = tid >> 6;
    const int wm = (wid >> 1) * 64;
    const int wn = (wid & 1) * 64;
    const int fr = lane & 15;
    const int fk = (lane >> 4) * 8;

    f32x4 acc[4][4];
#pragma unroll
    for (int i = 0; i < 4; ++i)
#pragma unroll
        for (int j = 0; j < 4; ++j) acc[i][j] = (f32x4)0.f;

    float4 av[4], bv[4];
#pragma unroll
    for (int q = 0; q < 4; ++q) {
        av[q] = *(const float4*)(arow + skh + 4 * q);
        bv[q] = *(const float4*)(brow + skh + 4 * q);
    }

    for (int kb = 0; kb < D_IN; kb += 32) {
        __syncthreads();
        {
            const float* f = (const float*)av;
            unsigned hp[8], lp[8];
#pragma unroll
            for (int p = 0; p < 8; ++p) split2(f[2 * p], f[2 * p + 1], hp[p], lp[p]);
            *(uint4*)&Ah[srow * LDA + skh]     = make_uint4(hp[0], hp[1], hp[2], hp[3]);
            *(uint4*)&Ah[srow * LDA + skh + 8] = make_uint4(hp[4], hp[5], hp[6], hp[7]);
            *(uint4*)&Al[srow * LDA + skh]     = make_uint4(lp[0], lp[1], lp[2], lp[3]);
            *(uint4*)&Al[srow * LDA + skh + 8] = make_uint4(lp[4], lp[5], lp[6], lp[7]);
        }
        {
            const float* f = (const float*)bv;
            unsigned hp[8], lp[8];
#pragma unroll
            for (int p = 0; p < 8; ++p) split2(f[2 * p], f[2 * p + 1], hp[p], lp[p]);
            *(uint4*)&Bh[srow * LDA + skh]     = make_uint4(hp[0], hp[1], hp[2], hp[3]);
            *(uint4*)&Bh[srow * LDA + skh + 8] = make_uint4(hp[4], hp[5], hp[6], hp[7]);
            *(uint4*)&Bl[srow * LDA + skh]     = make_uint4(lp[0], lp[1], lp[2], lp[3]);
            *(uint4*)&Bl[srow * LDA + skh + 8] = make_uint4(lp[4], lp[5], lp[6], lp[7]);
        }
        __syncthreads();

        if (kb + 32 < D_IN) {
#pragma unroll
            for (int q = 0; q < 4; ++q) {
                av[q] = *(const float4*)(arow + kb + 32 + skh + 4 * q);
                bv[q] = *(const float4*)(brow + kb + 32 + skh + 4 * q);
            }
        }

        short8 afh[4], afl[4], bfh[4], bfl[4];
#pragma unroll
        for (int i = 0; i < 4; ++i) {
            afh[i] = *(const short8*)&Ah[(wm + i * 16 + fr) * LDA + fk];
            afl[i] = *(const short8*)&Al[(wm + i * 16 + fr) * LDA + fk];
            bfh[i] = *(const short8*)&Bh[(wn + i * 16 + fr) * LDA + fk];
            bfl[i] = *(const short8*)&Bl[(wn + i * 16 + fr) * LDA + fk];
        }
#pragma unroll
        for (int i = 0; i < 4; ++i)
#pragma unroll
            for (int j = 0; j < 4; ++j) {
                acc[i][j] = __builtin_amdgcn_mfma_f32_16x16x32_bf16(afh[i], bfh[j], acc[i][j], 0, 0, 0);
                acc[i][j] = __builtin_amdgcn_mfma_f32_16x16x32_bf16(afh[i], bfl[j], acc[i][j], 0, 0, 0);
                acc[i][j] = __builtin_amdgcn_mfma_f32_16x16x32_bf16(afl[i], bfh[j], acc[i][j], 0, 0, 0);
            }
    }

    float biasv[4];
#pragma unroll
    for (int j = 0; j < 4; ++j) {
        const int col = n0 + wn + j * 16 + fr;
        biasv[j] = b_ih[col] + b_hh[col];
    }
    const int rbase = (lane >> 4) * 4;
#pragma unroll
    for (int i = 0; i < 4; ++i)
#pragma unroll
        for (int j = 0; j < 4; ++j) {
            const int col = n0 + wn + j * 16 + fr;
#pragma unroll
            for (int r = 0; r < 4; ++r) {
                const int row = m0 + wm + i * 16 + rbase + r;
                xg[(size_t)row * G4 + col] = __float2half_rn(acc[i][j][r] + biasv[j]);
            }
        }
}

// fast tanh via v_exp_f32; ~1e-7 abs error, no overflow (e<=1).
__device__ __forceinline__ float fast_tanh(float x) {
    const float e = __expf(-2.f * fabsf(x));
    const float r = __fdividef(1.f - e, 1.f + e);
    return copysignf(r, x);
}

// ---------------------------------------------------------------------------
// Phase B: persistent cooperative recurrence. R3 protocol (R4: compile fix —
// ext_vector u32x4 through inline asm; + sched_barrier(0) after the poll
// vmcnt wait, rule #18):
//  - Exchange via tag-colocated 16-B chunks (chunk_glb), double-buffered by
//    t&1. Producer: ONE global_store_dwordx4 sc0 sc1 per chunk (store IS the
//    publish -- no drain, no flag trip). Consumer: poll global_load_dwordx4
//    sc0 sc1; the tag-detecting load delivers the data. One hop each way.
//  - Per-wave quarter polling: wave wv polls producers [32wv,32wv+32), stages
//    its own K-quarter of Hh/Hl -> no pre-MFMA __syncthreads; stragglers
//    overlap with staging of arrived chunks.
//  - out[] stores are plain cached (visible at kernel end); off critical path.
//  - Safety: producer overwrites slot (tag t+1) only after observing tag t
//    from ALL 128 producers (its 4 waves cover them); each producer published
//    tag t only after consuming tag t-1 from this slot. Loads complete (data
//    returned, vmcnt) before later stores issue => no torn overwrite window.
// ---------------------------------------------------------------------------
__global__ void __launch_bounds__(256, 1)
lstm_rec(const __half* __restrict__ xg, const float* __restrict__ Whh,
         float* __restrict__ out)
{
    extern __shared__ char smc[];
    unsigned short* Wh_s = (unsigned short*)smc;                 // 24*776*2 = 37248
    unsigned short* Wl_s = (unsigned short*)(smc + 37248);       // 37248
    unsigned short* Hh_s = (unsigned short*)(smc + 74496);       // 16*776*2 = 24832
    unsigned short* Hl_s = (unsigned short*)(smc + 99328);       // 24832
    float*          rbuf = (float*)(smc + 124160);               // 8192
    float*          G    = (float*)(smc + 132352);               // 1536
    unsigned*       hstage = (unsigned*)(smc + 133888);          // 96*4 = 384 -> 134272

    const int tid = threadIdx.x;
    const int wg  = blockIdx.x;
    const int c   = wg & 1;        // batch group (sync domain)
    const int r   = wg >> 1;       // unit group 0..127 (this WG's producer id)
    const int u0  = r * 6;
    const int b0  = c * 16;

    // ---- load + split W_hh slice once: rows (gate*768 + u0 + j) ----
    for (int i = tid; i < 24 * 192; i += 256) {
        const int rr2 = i / 192;             // local row 0..23
        const int kc = (i % 192) * 4;
        const int gate = rr2 / 6, j = rr2 % 6;
        const float4 v = *(const float4*)&Whh[(size_t)(gate * H_SZ + u0 + j) * H_SZ + kc];
        unsigned h01, l01, h23, l23;
        split2(v.x, v.y, h01, l01);
        split2(v.z, v.w, h23, l23);
        *(uint2*)&Wh_s[rr2 * HPAD + kc] = make_uint2(h01, h23);
        *(uint2*)&Wl_s[rr2 * HPAD + kc] = make_uint2(l01, l23);
    }
    __syncthreads();

    // MFMA / poll roles
    const int lane = tid & 63;
    const int wv   = tid >> 6;               // wave = K-quarter owner
    const int fr   = lane & 15;              // frag row (W) / batch row (h)
    const int fkb  = (lane >> 4) * 8;        // frag k offset
    const int rb4  = (lane >> 4) * 4;        // D frag row base
    const int rr   = wv * 32 + (lane >> 1);  // producer this lane polls
    const int bs   = (lane & 1) * 8;         // batch subset base (8 batches)

    // combine-phase role (threads 0..95)
    const int cj = tid % 6;                  // unit within group
    const int cb = tid / 6;                  // batch within group
    float c_reg = 0.f;                       // cell state, register-resident

    for (int t = 0; t < T_LEN; ++t) {
        // ---- prefetch xg[t] for the combine (independent of h) ----
        float xpi = 0.f, xpf = 0.f, xpg = 0.f, xpo = 0.f;
        if (tid < 96) {
            const size_t xbase = ((size_t)t * B_SZ + (b0 + cb)) * G4 + u0 + cj;
            xpi = __half2float(xg[xbase + 0 * H_SZ]);
            xpf = __half2float(xg[xbase + 1 * H_SZ]);
            xpg = __half2float(xg[xbase + 2 * H_SZ]);
            xpo = __half2float(xg[xbase + 3 * H_SZ]);
        }

        if (t > 0) {
            // ---- poll + stage this wave's K-quarter (no barrier needed:
            //      frag reads below touch only columns this wave writes) ----
            const u32x4* cbase = &chunk_glb[((((size_t)(t & 1)) * 2 + c) * 128 + rr) * 32
                                            + (lane & 1) * 16];
            unsigned pend = 0xFFFFu;
            while (pend) {
                u32x4 cv[16];
#pragma unroll
                for (int q = 0; q < 16; ++q) {
                    if (pend & (1u << q)) {
                        asm volatile("global_load_dwordx4 %0, %1, off sc0 sc1"
                                     : "=v"(cv[q]) : "v"(cbase + q));
                    }
                }
                asm volatile("s_waitcnt vmcnt(0)" ::: "memory");
                __builtin_amdgcn_sched_barrier(0);   // rule #18: don't use cv early
#pragma unroll
                for (int q = 0; q < 16; ++q) {
                    if ((pend & (1u << q)) && cv[q].x == (unsigned)t) {
                        const int b = bs + (q >> 1);
                        const int k = 6 * rr + (q & 1) * 3;
                        Hh_s[b * HPAD + k + 0] = (unsigned short)(cv[q].y >> 16);
                        Hl_s[b * HPAD + k + 0] = (unsigned short)(cv[q].y & 0xffffu);
                        Hh_s[b * HPAD + k + 1] = (unsigned short)(cv[q].z >> 16);
                        Hl_s[b * HPAD + k + 1] = (unsigned short)(cv[q].z & 0xffffu);
                        Hh_s[b * HPAD + k + 2] = (unsigned short)(cv[q].w >> 16);
                        Hl_s[b * HPAD + k + 2] = (unsigned short)(cv[q].w & 0xffffu);
                        pend &= ~(1u << q);
                    }
                }
            }
            asm volatile("s_waitcnt lgkmcnt(0)" ::: "memory");
            __builtin_amdgcn_sched_barrier(0);

            // ---- dot via MFMA: wave wv owns k in [192*wv, 192*wv+192) ----
            f32x4 acc0 = (f32x4)0.f, acc1 = (f32x4)0.f;
            const int kwb = wv * 192;
#pragma unroll
            for (int ksd = 0; ksd < 6; ++ksd) {
                const int ko = kwb + ksd * 32 + fkb;
                const short8 bh  = *(const short8*)&Hh_s[fr * HPAD + ko];
                const short8 bl  = *(const short8*)&Hl_s[fr * HPAD + ko];
                const short8 a0h = *(const short8*)&Wh_s[fr * HPAD + ko];
                const short8 a0l = *(const short8*)&Wl_s[fr * HPAD + ko];
                const short8 a1h = *(const short8*)&Wh_s[(8 + fr) * HPAD + ko];
                const short8 a1l = *(const short8*)&Wl_s[(8 + fr) * HPAD + ko];
                acc0 = __builtin_amdgcn_mfma_f32_16x16x32_bf16(a0h, bh, acc0, 0, 0, 0);
                acc0 = __builtin_amdgcn_mfma_f32_16x16x32_bf16(a0h, bl, acc0, 0, 0, 0);
                acc0 = __builtin_amdgcn_mfma_f32_16x16x32_bf16(a0l, bh, acc0, 0, 0, 0);
                acc1 = __builtin_amdgcn_mfma_f32_16x16x32_bf16(a1h, bh, acc1, 0, 0, 0);
                acc1 = __builtin_amdgcn_mfma_f32_16x16x32_bf16(a1h, bl, acc1, 0, 0, 0);
                acc1 = __builtin_amdgcn_mfma_f32_16x16x32_bf16(a1l, bh, acc1, 0, 0, 0);
            }

            // ---- stash partials for cross-wave K-reduce ----
#pragma unroll
            for (int rix = 0; rix < 4; ++rix) {
                rbuf[((rb4 + rix) * 16 + fr) * 4 + wv]      = acc0[rix];
                rbuf[((16 + rb4 + rix) * 16 + fr) * 4 + wv] = acc1[rix];
            }
        }
        __syncthreads();                       // B1: rbuf complete

        if (t > 0) {
            for (int oi = tid; oi < 384; oi += 256) {
                const int row = oi >> 4, colr = oi & 15;
                const int idx = (row < 16) ? oi : ((row + 8) * 16 + colr);
                const float4 v = *(const float4*)&rbuf[idx * 4];
                G[oi] = v.x + v.y + v.z + v.w;
            }
        } else {
            for (int i = tid; i < 384; i += 256) G[i] = 0.f;
        }
        __syncthreads();                       // B2: G ready

        // ---- gate combine: threads 0..95, one (unit, batch) each ----
        if (tid < 96) {
            const float pi = G[(0 * 6 + cj) * 16 + cb] + xpi;
            const float pf = G[(1 * 6 + cj) * 16 + cb] + xpf;
            const float pg = G[(2 * 6 + cj) * 16 + cb] + xpg;
            const float po = G[(3 * 6 + cj) * 16 + cb] + xpo;
            const float ig = 1.f / (1.f + __expf(-pi));
            const float fg = 1.f / (1.f + __expf(-pf));
            const float gg = fast_tanh(pg);
            const float og = 1.f / (1.f + __expf(-po));
            c_reg = fg * c_reg + ig * gg;
            const float h = og * fast_tanh(c_reg);
            // output: plain cached store, off the critical path
            out[((size_t)(b0 + cb) * T_LEN + t) * H_SZ + u0 + cj] = h;
            // pack (bf16hi|bf16lo) for the exchange (same trunc-split as MFMA)
            const unsigned uh = __float_as_uint(h) & 0xffff0000u;
            const float lo = h - __uint_as_float(uh);
            hstage[tid] = uh | (__float_as_uint(lo) >> 16);
        }
        __syncthreads();                       // B3: hstage complete

        // ---- publish: 32 chunks, tag+data in one 16-B store each ----
        if (tid < 32) {
            u32x4 val;
            val.x = (unsigned)(t + 1);
            val.y = hstage[3 * tid];
            val.z = hstage[3 * tid + 1];
            val.w = hstage[3 * tid + 2];
            u32x4* dst = &chunk_glb[((((size_t)((t + 1) & 1)) * 2 + c) * 128 + r) * 32 + tid];
            asm volatile("global_store_dwordx4 %0, %1, off sc0 sc1"
                         :: "v"(dst), "v"(val) : "memory");
        }
    }
}

// ---------------------------------------------------------------------------
extern "C" void kernel_launch(void* const* d_in, const int* in_sizes, int n_in,
                              void* d_out, int out_size, void* d_ws, size_t ws_size,
                              hipStream_t stream)
{
    (void)in_sizes; (void)n_in; (void)out_size; (void)ws_size;
    const float* hidden = (const float*)d_in[0];
    const float* W_ih   = (const float*)d_in[1];
    const float* W_hh   = (const float*)d_in[2];
    const float* b_ih   = (const float*)d_in[3];
    const float* b_hh   = (const float*)d_in[4];
    float* out = (float*)d_out;

    __half* xg = (__half*)d_ws;   // 1024*32*3072*2 = 201,326,592 B

    zero_chunks<<<dim3(64), dim3(256), 0, stream>>>();   // clear stale tags
    xg_gemm<<<dim3(G4 / 128, (B_SZ * T_LEN) / 128), dim3(256), 0, stream>>>(
        hidden, W_ih, b_ih, b_hh, xg);

    const int smem = 134272;  // W 74496 + H 49664 + rbuf 8192 + G 1536 + hstage 384
    (void)hipFuncSetAttribute((const void*)lstm_rec,
                              hipFuncAttributeMaxDynamicSharedMemorySize, smem);
    void* args[] = { (void*)&xg, (void*)&W_hh, (void*)&out };
    (void)hipLaunchCooperativeKernel((void*)lstm_rec, dim3(256), dim3(256),
                                     args, (unsigned)smem, stream);
}

// Round 5
// 6711.562 us; speedup vs baseline: 1.2150x; 1.2150x over previous
//
#include <hip/hip_runtime.h>
#include <hip/hip_fp16.h>

#define T_LEN 1024
#define B_SZ  32
#define D_IN  768
#define H_SZ  768
#define G4    3072   // 4*H
#define FPAD  32     // flag padding: 1 flag per 128-byte line
#define LDA   40     // xg_gemm: padded LDS row stride (bf16) for 32-wide K tiles

typedef __attribute__((ext_vector_type(8))) short short8;  // 8 bf16 (4 VGPRs)
typedef __attribute__((ext_vector_type(4))) float f32x4;   // MFMA 16x16 C/D frag

// bitwise fp32 -> bf16 hi/lo split (exact residual; 3-term MFMA error ~2^-16 rel)
__device__ __forceinline__ void split2(float x0, float x1, unsigned& hp, unsigned& lp)
{
    const unsigned u0 = __float_as_uint(x0);
    const unsigned u1 = __float_as_uint(x1);
    const unsigned h0 = u0 & 0xffff0000u, h1 = u1 & 0xffff0000u;
    hp = (h0 >> 16) | h1;
    const float l0 = x0 - __uint_as_float(h0);
    const float l1 = x1 - __uint_as_float(h1);
    lp = (__float_as_uint(l0) >> 16) | (__float_as_uint(l1) & 0xffff0000u);
}

// ---------------------------------------------------------------------------
// Phase A: split-bf16 3-term MFMA GEMM (verified R1/R2: ~0.36 ms, absmax
// unchanged). R5 change: epilogue writes xg in CONSUMER-DENSE layout
//   xg[t][c][r][gate][cb][cj]  (addr = ((t*2+c)*128 + r)*384 + gate*96 +
//   cb*6 + cj), so lstm_rec's per-step prefetch is 4 x 192-B contiguous
//   coalesced runs instead of 64 scattered 12-B slivers (~4-5x HBM overfetch).
// ---------------------------------------------------------------------------
__global__ __launch_bounds__(256, 2)
void xg_gemm(const float* __restrict__ hidden, const float* __restrict__ W_ih,
             const float* __restrict__ b_ih, const float* __restrict__ b_hh,
             __half* __restrict__ xg)
{
    __shared__ unsigned short Ah[128 * LDA];
    __shared__ unsigned short Al[128 * LDA];
    __shared__ unsigned short Bh[128 * LDA];
    __shared__ unsigned short Bl[128 * LDA];

    const int tid = threadIdx.x;
    const int n0 = blockIdx.x * 128;
    const int m0 = blockIdx.y * 128;

    const int srow = tid >> 1;
    const int skh  = (tid & 1) * 16;
    const int m = m0 + srow;
    const float* arow = hidden + ((size_t)(m & 31) * T_LEN + (m >> 5)) * D_IN;
    const float* brow = W_ih + (size_t)(n0 + srow) * D_IN;

    const int lane = tid & 63;
    const int wid  = tid >> 6;
    const int wm = (wid >> 1) * 64;
    const int wn = (wid & 1) * 64;
    const int fr = lane & 15;
    const int fk = (lane >> 4) * 8;

    f32x4 acc[4][4];
#pragma unroll
    for (int i = 0; i < 4; ++i)
#pragma unroll
        for (int j = 0; j < 4; ++j) acc[i][j] = (f32x4)0.f;

    float4 av[4], bv[4];
#pragma unroll
    for (int q = 0; q < 4; ++q) {
        av[q] = *(const float4*)(arow + skh + 4 * q);
        bv[q] = *(const float4*)(brow + skh + 4 * q);
    }

    for (int kb = 0; kb < D_IN; kb += 32) {
        __syncthreads();
        {
            const float* f = (const float*)av;
            unsigned hp[8], lp[8];
#pragma unroll
            for (int p = 0; p < 8; ++p) split2(f[2 * p], f[2 * p + 1], hp[p], lp[p]);
            *(uint4*)&Ah[srow * LDA + skh]     = make_uint4(hp[0], hp[1], hp[2], hp[3]);
            *(uint4*)&Ah[srow * LDA + skh + 8] = make_uint4(hp[4], hp[5], hp[6], hp[7]);
            *(uint4*)&Al[srow * LDA + skh]     = make_uint4(lp[0], lp[1], lp[2], lp[3]);
            *(uint4*)&Al[srow * LDA + skh + 8] = make_uint4(lp[4], lp[5], lp[6], lp[7]);
        }
        {
            const float* f = (const float*)bv;
            unsigned hp[8], lp[8];
#pragma unroll
            for (int p = 0; p < 8; ++p) split2(f[2 * p], f[2 * p + 1], hp[p], lp[p]);
            *(uint4*)&Bh[srow * LDA + skh]     = make_uint4(hp[0], hp[1], hp[2], hp[3]);
            *(uint4*)&Bh[srow * LDA + skh + 8] = make_uint4(hp[4], hp[5], hp[6], hp[7]);
            *(uint4*)&Bl[srow * LDA + skh]     = make_uint4(lp[0], lp[1], lp[2], lp[3]);
            *(uint4*)&Bl[srow * LDA + skh + 8] = make_uint4(lp[4], lp[5], lp[6], lp[7]);
        }
        __syncthreads();

        if (kb + 32 < D_IN) {
#pragma unroll
            for (int q = 0; q < 4; ++q) {
                av[q] = *(const float4*)(arow + kb + 32 + skh + 4 * q);
                bv[q] = *(const float4*)(brow + kb + 32 + skh + 4 * q);
            }
        }

        short8 afh[4], afl[4], bfh[4], bfl[4];
#pragma unroll
        for (int i = 0; i < 4; ++i) {
            afh[i] = *(const short8*)&Ah[(wm + i * 16 + fr) * LDA + fk];
            afl[i] = *(const short8*)&Al[(wm + i * 16 + fr) * LDA + fk];
            bfh[i] = *(const short8*)&Bh[(wn + i * 16 + fr) * LDA + fk];
            bfl[i] = *(const short8*)&Bl[(wn + i * 16 + fr) * LDA + fk];
        }
#pragma unroll
        for (int i = 0; i < 4; ++i)
#pragma unroll
            for (int j = 0; j < 4; ++j) {
                acc[i][j] = __builtin_amdgcn_mfma_f32_16x16x32_bf16(afh[i], bfh[j], acc[i][j], 0, 0, 0);
                acc[i][j] = __builtin_amdgcn_mfma_f32_16x16x32_bf16(afh[i], bfl[j], acc[i][j], 0, 0, 0);
                acc[i][j] = __builtin_amdgcn_mfma_f32_16x16x32_bf16(afl[i], bfh[j], acc[i][j], 0, 0, 0);
            }
    }

    // epilogue: C/D layout col=lane&15, row=(lane>>4)*4+reg; consumer-dense
    // xg addressing (see header comment).
    const int rbase = (lane >> 4) * 4;
#pragma unroll
    for (int j = 0; j < 4; ++j) {
        const int gg = n0 + wn + j * 16 + fr;       // global gate-column
        const int gate = gg / 768;
        const int u    = gg - gate * 768;
        const int rq   = u / 6;
        const int cj   = u - rq * 6;
        const float bias = b_ih[gg] + b_hh[gg];
        const size_t cbase = (size_t)rq * 384 + gate * 96 + cj;
#pragma unroll
        for (int i = 0; i < 4; ++i) {
#pragma unroll
            for (int rx = 0; rx < 4; ++rx) {
                const int mm = m0 + wm + i * 16 + rbase + rx;
                const int t = mm >> 5, b = mm & 31;
                const size_t addr = (((size_t)t * 2 + (b >> 4)) * 128) * 384
                                    + cbase + (b & 15) * 6;
                xg[addr] = __float2half_rn(acc[i][j][rx] + bias);
            }
        }
    }
}

// ---------------------------------------------------------------------------
// Zero the padded per-WG progress flags (2 domains x 128 flags x 32 stride).
// ---------------------------------------------------------------------------
__global__ void zero_cnt(unsigned* flags) {
    flags[blockIdx.x * 1024 + threadIdx.x] = 0u;
}

// fast tanh via v_exp_f32; ~1e-7 abs error, no overflow (e<=1).
__device__ __forceinline__ float fast_tanh(float x) {
    const float e = __expf(-2.f * fabsf(x));
    const float r = __fdividef(1.f - e, 1.f + e);
    return copysignf(r, x);
}

// ---------------------------------------------------------------------------
// Phase B: persistent cooperative recurrence — EXACT R1 structure (measured
// 6.36 ms, the session best): per-WG line-padded flags, relaxed agent-scope
// h exchange through out[], single-phase 128-flag poll with s_sleep backoff,
// scalar dot + LDS partial reduce, fast_tanh combine, vmcnt-drained publish.
// R5's only change: xg prefetch uses the consumer-dense layout (4 x 192-B
// coalesced runs; thread address = base + gate*96 + tid).
// ---------------------------------------------------------------------------
__global__ void __launch_bounds__(256, 1)
lstm_rec(const __half* __restrict__ xg, const float* __restrict__ Whh,
         float* __restrict__ out, unsigned* __restrict__ flags)
{
    extern __shared__ float sm[];
    float* Wsl = sm;                         // 24*768 = 18432 floats
    float* hsl = sm + 24 * H_SZ;             // 12288 floats (union with P)
    float* G   = sm + 24 * H_SZ + 12288;     // 384 floats

    const int tid = threadIdx.x;
    const int wg  = blockIdx.x;
    const int c   = wg & 1;        // batch group (sync domain)
    const int r   = wg >> 1;       // unit group 0..127
    const int u0  = r * 6;
    const int b0  = c * 16;

    // ---- load W_hh slice once: rows (gate*768 + u0 + j), gate<4, j<6 ----
    for (int i = tid; i < 24 * 192; i += 256) {
        const int rr = i / 192;              // local row 0..23
        const int kc = (i % 192) * 4;
        const int gate = rr / 6, j = rr % 6;
        const float4 v = *(const float4*)&Whh[(size_t)(gate * H_SZ + u0 + j) * H_SZ + kc];
        *(float4*)&Wsl[rr * H_SZ + kc] = v;
    }

    // dot-phase role
    const int ks     = tid & 31;             // K segment (k = 4*ks + 128*jj)
    const int tileId = tid >> 5;             // 0..7
    const int tr = (tileId & 1) * 12;        // row tile base
    const int tb = (tileId >> 1) * 4;        // batch tile base

    // combine-phase role (threads 0..95)
    const int cj = tid % 6;                  // unit within group
    const int cb = tid / 6;                  // batch within group
    float c_reg = 0.f;                       // cell state, register-resident

    unsigned* myflags = flags + c * 128 * FPAD;

    __builtin_amdgcn_fence(__ATOMIC_ACQUIRE, "agent");  // once: clear poison
    __syncthreads();

    for (int t = 0; t < T_LEN; ++t) {
        // ---- prefetch xg[t]: consumer-dense, 4 x 192-B coalesced runs ----
        float xpi = 0.f, xpf = 0.f, xpg = 0.f, xpo = 0.f;
        if (tid < 96) {
            const size_t xbase = (((size_t)t * 2 + c) * 128 + r) * 384 + tid;
            xpi = __half2float(xg[xbase + 0 * 96]);
            xpf = __half2float(xg[xbase + 1 * 96]);
            xpg = __half2float(xg[xbase + 2 * 96]);
            xpo = __half2float(xg[xbase + 3 * 96]);
        }

        if (t == 0) {
            for (int i = tid; i < 384; i += 256) G[i] = 0.f;  // h_prev = 0
            __syncthreads();
        } else {
            // ---- wait: all 128 WGs of this domain finished step t-1 ----
            if (tid < 128) {
                while (__hip_atomic_load(&myflags[tid * FPAD], __ATOMIC_RELAXED,
                                         __HIP_MEMORY_SCOPE_AGENT) < (unsigned)t) {
                    __builtin_amdgcn_s_sleep(2);   // backoff: cut L3 poll traffic
                }
            }
            __syncthreads();

            // ---- stage h_prev[b0..b0+16][:] into LDS via coherent dword
            //      loads (no fence needed). b = i/3, k = tid + (i%3)*256. ----
            float hreg[48];
#pragma unroll
            for (int i = 0; i < 48; ++i) {
                const int b = i / 3;
                const int k = tid + (i % 3) * 256;
                hreg[i] = __hip_atomic_load(
                    &out[((size_t)(b0 + b) * T_LEN + (t - 1)) * H_SZ + k],
                    __ATOMIC_RELAXED, __HIP_MEMORY_SCOPE_AGENT);
            }
#pragma unroll
            for (int i = 0; i < 48; ++i) {
                const int b = i / 3;
                const int k = tid + (i % 3) * 256;
                hsl[b * H_SZ + k] = hreg[i];
            }
            __syncthreads();

            // ---- dot: acc[12 rows][4 batches] over 24-element K segment ----
            float acc[12][4];
#pragma unroll
            for (int a = 0; a < 12; ++a)
#pragma unroll
                for (int q = 0; q < 4; ++q) acc[a][q] = 0.f;

            for (int jj = 0; jj < 6; ++jj) {
                const int k = ks * 4 + jj * 128;   // lanes stride-1 in k
                float4 hv[4];
#pragma unroll
                for (int q = 0; q < 4; ++q)
                    hv[q] = *(const float4*)&hsl[(tb + q) * H_SZ + k];
#pragma unroll
                for (int a = 0; a < 12; ++a) {
                    const float4 wv = *(const float4*)&Wsl[(tr + a) * H_SZ + k];
#pragma unroll
                    for (int q = 0; q < 4; ++q) {
                        acc[a][q] = fmaf(wv.x, hv[q].x, acc[a][q]);
                        acc[a][q] = fmaf(wv.y, hv[q].y, acc[a][q]);
                        acc[a][q] = fmaf(wv.z, hv[q].z, acc[a][q]);
                        acc[a][q] = fmaf(wv.w, hv[q].w, acc[a][q]);
                    }
                }
            }
            __syncthreads();                 // hsl reads done -> reuse as P

            // ---- write partials P[out 0..383][ks 0..31] ----
            float* P = hsl;
#pragma unroll
            for (int a = 0; a < 12; ++a)
#pragma unroll
                for (int q = 0; q < 4; ++q)
                    P[((tr + a) * 16 + (tb + q)) * 32 + ks] = acc[a][q];
            __syncthreads();

            // ---- reduce (diagonal reads: bank-conflict-free) ----
            for (int oi = tid; oi < 384; oi += 256) {
                float s = 0.f;
#pragma unroll
                for (int kk = 0; kk < 32; ++kk) {
                    const int k2 = (kk + oi) & 31;
                    s += P[oi * 32 + k2];
                }
                G[oi] = s;
            }
            __syncthreads();
        }

        // ---- gate combine: threads 0..95, one (unit, batch) each ----
        if (tid < 96) {
            const float pi = G[(0 * 6 + cj) * 16 + cb] + xpi;
            const float pf = G[(1 * 6 + cj) * 16 + cb] + xpf;
            const float pg = G[(2 * 6 + cj) * 16 + cb] + xpg;
            const float po = G[(3 * 6 + cj) * 16 + cb] + xpo;
            const float ig = 1.f / (1.f + __expf(-pi));
            const float fg = 1.f / (1.f + __expf(-pf));
            const float gg = fast_tanh(pg);
            const float og = 1.f / (1.f + __expf(-po));
            c_reg = fg * c_reg + ig * gg;
            const float h = og * fast_tanh(c_reg);
            // write-through to the device coherence point; readers bypass too
            __hip_atomic_store(&out[((size_t)(b0 + cb) * T_LEN + t) * H_SZ + u0 + cj],
                               h, __ATOMIC_RELAXED, __HIP_MEMORY_SCOPE_AGENT);
        }
        // drain only vmem stores, then barrier so ALL waves' stores are done
        asm volatile("s_waitcnt vmcnt(0)" ::: "memory");
        __syncthreads();

        // ---- publish: one relaxed flag store (flag = steps completed) ----
        if (tid == 0) {
            __hip_atomic_store(&myflags[r * FPAD], (unsigned)(t + 1),
                               __ATOMIC_RELAXED, __HIP_MEMORY_SCOPE_AGENT);
        }
    }
}

// ---------------------------------------------------------------------------
extern "C" void kernel_launch(void* const* d_in, const int* in_sizes, int n_in,
                              void* d_out, int out_size, void* d_ws, size_t ws_size,
                              hipStream_t stream)
{
    (void)in_sizes; (void)n_in; (void)out_size; (void)ws_size;
    const float* hidden = (const float*)d_in[0];
    const float* W_ih   = (const float*)d_in[1];
    const float* W_hh   = (const float*)d_in[2];
    const float* b_ih   = (const float*)d_in[3];
    const float* b_hh   = (const float*)d_in[4];
    float* out = (float*)d_out;

    __half* xg = (__half*)d_ws;                                  // 201,326,592 B
    unsigned* flags = (unsigned*)((char*)d_ws +
                      (size_t)T_LEN * B_SZ * G4 * sizeof(__half)); // 8192 u32

    zero_cnt<<<dim3(8), dim3(1024), 0, stream>>>(flags);
    xg_gemm<<<dim3(G4 / 128, (B_SZ * T_LEN) / 128), dim3(256), 0, stream>>>(
        hidden, W_ih, b_ih, b_hh, xg);

    const int smem = (24 * H_SZ + 12288 + 384) * (int)sizeof(float);  // 124,416 B
    (void)hipFuncSetAttribute((const void*)lstm_rec,
                              hipFuncAttributeMaxDynamicSharedMemorySize, smem);
    void* args[] = { (void*)&xg, (void*)&W_hh, (void*)&out, (void*)&flags };
    (void)hipLaunchCooperativeKernel((void*)lstm_rec, dim3(256), dim3(256),
                                     args, (unsigned)smem, stream);
}

// Round 6
// 5676.326 us; speedup vs baseline: 1.4366x; 1.1824x over previous
//
#include <hip/hip_runtime.h>
#include <hip/hip_fp16.h>

#define T_LEN 1024
#define B_SZ  32
#define D_IN  768
#define H_SZ  768
#define G4    3072   // 4*H
#define FPAD  32     // flag padding: 1 flag per 128-byte line
#define LDA   40     // xg_gemm: padded LDS row stride (bf16) for 32-wide K tiles

typedef __attribute__((ext_vector_type(8))) short short8;  // 8 bf16 (4 VGPRs)
typedef __attribute__((ext_vector_type(4))) float f32x4;   // MFMA frag / 16B load

// bitwise fp32 -> bf16 hi/lo split (exact residual; 3-term MFMA error ~2^-16 rel)
__device__ __forceinline__ void split2(float x0, float x1, unsigned& hp, unsigned& lp)
{
    const unsigned u0 = __float_as_uint(x0);
    const unsigned u1 = __float_as_uint(x1);
    const unsigned h0 = u0 & 0xffff0000u, h1 = u1 & 0xffff0000u;
    hp = (h0 >> 16) | h1;
    const float l0 = x0 - __uint_as_float(h0);
    const float l1 = x1 - __uint_as_float(h1);
    lp = (__float_as_uint(l0) >> 16) | (__float_as_uint(l1) & 0xffff0000u);
}

// ---------------------------------------------------------------------------
// Phase A: split-bf16 3-term MFMA GEMM (verified R1/R2: ~0.36 ms). Epilogue
// writes xg in consumer-dense layout xg[t][c][r][gate][cb][cj] (verified R5:
// FETCH 664->370 MB). Unchanged.
// ---------------------------------------------------------------------------
__global__ __launch_bounds__(256, 2)
void xg_gemm(const float* __restrict__ hidden, const float* __restrict__ W_ih,
             const float* __restrict__ b_ih, const float* __restrict__ b_hh,
             __half* __restrict__ xg)
{
    __shared__ unsigned short Ah[128 * LDA];
    __shared__ unsigned short Al[128 * LDA];
    __shared__ unsigned short Bh[128 * LDA];
    __shared__ unsigned short Bl[128 * LDA];

    const int tid = threadIdx.x;
    const int n0 = blockIdx.x * 128;
    const int m0 = blockIdx.y * 128;

    const int srow = tid >> 1;
    const int skh  = (tid & 1) * 16;
    const int m = m0 + srow;
    const float* arow = hidden + ((size_t)(m & 31) * T_LEN + (m >> 5)) * D_IN;
    const float* brow = W_ih + (size_t)(n0 + srow) * D_IN;

    const int lane = tid & 63;
    const int wid  = tid >> 6;
    const int wm = (wid >> 1) * 64;
    const int wn = (wid & 1) * 64;
    const int fr = lane & 15;
    const int fk = (lane >> 4) * 8;

    f32x4 acc[4][4];
#pragma unroll
    for (int i = 0; i < 4; ++i)
#pragma unroll
        for (int j = 0; j < 4; ++j) acc[i][j] = (f32x4)0.f;

    float4 av[4], bv[4];
#pragma unroll
    for (int q = 0; q < 4; ++q) {
        av[q] = *(const float4*)(arow + skh + 4 * q);
        bv[q] = *(const float4*)(brow + skh + 4 * q);
    }

    for (int kb = 0; kb < D_IN; kb += 32) {
        __syncthreads();
        {
            const float* f = (const float*)av;
            unsigned hp[8], lp[8];
#pragma unroll
            for (int p = 0; p < 8; ++p) split2(f[2 * p], f[2 * p + 1], hp[p], lp[p]);
            *(uint4*)&Ah[srow * LDA + skh]     = make_uint4(hp[0], hp[1], hp[2], hp[3]);
            *(uint4*)&Ah[srow * LDA + skh + 8] = make_uint4(hp[4], hp[5], hp[6], hp[7]);
            *(uint4*)&Al[srow * LDA + skh]     = make_uint4(lp[0], lp[1], lp[2], lp[3]);
            *(uint4*)&Al[srow * LDA + skh + 8] = make_uint4(lp[4], lp[5], lp[6], lp[7]);
        }
        {
            const float* f = (const float*)bv;
            unsigned hp[8], lp[8];
#pragma unroll
            for (int p = 0; p < 8; ++p) split2(f[2 * p], f[2 * p + 1], hp[p], lp[p]);
            *(uint4*)&Bh[srow * LDA + skh]     = make_uint4(hp[0], hp[1], hp[2], hp[3]);
            *(uint4*)&Bh[srow * LDA + skh + 8] = make_uint4(hp[4], hp[5], hp[6], hp[7]);
            *(uint4*)&Bl[srow * LDA + skh]     = make_uint4(lp[0], lp[1], lp[2], lp[3]);
            *(uint4*)&Bl[srow * LDA + skh + 8] = make_uint4(lp[4], lp[5], lp[6], lp[7]);
        }
        __syncthreads();

        if (kb + 32 < D_IN) {
#pragma unroll
            for (int q = 0; q < 4; ++q) {
                av[q] = *(const float4*)(arow + kb + 32 + skh + 4 * q);
                bv[q] = *(const float4*)(brow + kb + 32 + skh + 4 * q);
            }
        }

        short8 afh[4], afl[4], bfh[4], bfl[4];
#pragma unroll
        for (int i = 0; i < 4; ++i) {
            afh[i] = *(const short8*)&Ah[(wm + i * 16 + fr) * LDA + fk];
            afl[i] = *(const short8*)&Al[(wm + i * 16 + fr) * LDA + fk];
            bfh[i] = *(const short8*)&Bh[(wn + i * 16 + fr) * LDA + fk];
            bfl[i] = *(const short8*)&Bl[(wn + i * 16 + fr) * LDA + fk];
        }
#pragma unroll
        for (int i = 0; i < 4; ++i)
#pragma unroll
            for (int j = 0; j < 4; ++j) {
                acc[i][j] = __builtin_amdgcn_mfma_f32_16x16x32_bf16(afh[i], bfh[j], acc[i][j], 0, 0, 0);
                acc[i][j] = __builtin_amdgcn_mfma_f32_16x16x32_bf16(afh[i], bfl[j], acc[i][j], 0, 0, 0);
                acc[i][j] = __builtin_amdgcn_mfma_f32_16x16x32_bf16(afl[i], bfh[j], acc[i][j], 0, 0, 0);
            }
    }

    const int rbase = (lane >> 4) * 4;
#pragma unroll
    for (int j = 0; j < 4; ++j) {
        const int gg = n0 + wn + j * 16 + fr;       // global gate-column
        const int gate = gg / 768;
        const int u    = gg - gate * 768;
        const int rq   = u / 6;
        const int cj   = u - rq * 6;
        const float bias = b_ih[gg] + b_hh[gg];
        const size_t cbase = (size_t)rq * 384 + gate * 96 + cj;
#pragma unroll
        for (int i = 0; i < 4; ++i) {
#pragma unroll
            for (int rx = 0; rx < 4; ++rx) {
                const int mm = m0 + wm + i * 16 + rbase + rx;
                const int t = mm >> 5, b = mm & 31;
                const size_t addr = (((size_t)t * 2 + (b >> 4)) * 128) * 384
                                    + cbase + (b & 15) * 6;
                xg[addr] = __float2half_rn(acc[i][j][rx] + bias);
            }
        }
    }
}

// ---------------------------------------------------------------------------
__global__ void zero_cnt(unsigned* flags) {
    flags[blockIdx.x * 1024 + threadIdx.x] = 0u;
}

// fast tanh via v_exp_f32; ~1e-7 abs error, no overflow (e<=1).
__device__ __forceinline__ float fast_tanh(float x) {
    const float e = __expf(-2.f * fabsf(x));
    const float r = __fdividef(1.f - e, 1.f + e);
    return copysignf(r, x);
}

// ---------------------------------------------------------------------------
// Phase B: persistent cooperative recurrence. R6: SAME protocol as R1/R5
// (measured best: per-WG line-padded flags, relaxed agent exchange through
// out[], sleep-backoff poll, vmcnt-drained publish) but 512 threads/WG:
//  - dot work per thread halves (576 FMA), 16 tiles of 6 rows x 4 batches
//  - h stage: 6 x global_load_dwordx4 sc0 sc1 (R4-proven asm; same bypass
//    semantics as the dword atomics, 8x fewer issues), rule-18 fenced
//  - reduce: one output per thread (384 of 512)
//  - 8 waves/CU double latency hiding during stage/prefetch
// ---------------------------------------------------------------------------
__global__ void __launch_bounds__(512, 1)
lstm_rec(const __half* __restrict__ xg, const float* __restrict__ Whh,
         float* __restrict__ out, unsigned* __restrict__ flags)
{
    extern __shared__ float sm[];
    float* Wsl = sm;                         // 24*768 = 18432 floats
    float* hsl = sm + 24 * H_SZ;             // 12288 floats (union with P)
    float* G   = sm + 24 * H_SZ + 12288;     // 384 floats

    const int tid = threadIdx.x;             // 0..511
    const int wg  = blockIdx.x;
    const int c   = wg & 1;        // batch group (sync domain)
    const int r   = wg >> 1;       // unit group 0..127
    const int u0  = r * 6;
    const int b0  = c * 16;

    // ---- load W_hh slice once: rows (gate*768 + u0 + j), gate<4, j<6 ----
    for (int i = tid; i < 24 * 192; i += 512) {
        const int rr = i / 192;              // local row 0..23
        const int kc = (i % 192) * 4;
        const int gate = rr / 6, j = rr % 6;
        const float4 v = *(const float4*)&Whh[(size_t)(gate * H_SZ + u0 + j) * H_SZ + kc];
        *(float4*)&Wsl[rr * H_SZ + kc] = v;
    }

    // dot-phase role: 16 tiles of (6 rows x 4 batches), 32-lane K split
    const int ks     = tid & 31;             // K segment (k = 4*ks + 128*jj)
    const int tileId = tid >> 5;             // 0..15
    const int tr = (tileId & 3) * 6;         // row tile base (0,6,12,18)
    const int tb = (tileId >> 2) * 4;        // batch tile base (0,4,8,12)

    // combine-phase role (threads 0..95)
    const int cj = tid % 6;                  // unit within group
    const int cb = tid / 6;                  // batch within group
    float c_reg = 0.f;                       // cell state, register-resident

    unsigned* myflags = flags + c * 128 * FPAD;

    __builtin_amdgcn_fence(__ATOMIC_ACQUIRE, "agent");  // once: clear poison
    __syncthreads();

    for (int t = 0; t < T_LEN; ++t) {
        // ---- prefetch xg[t]: consumer-dense, 4 x 192-B coalesced runs ----
        float xpi = 0.f, xpf = 0.f, xpg = 0.f, xpo = 0.f;
        if (tid < 96) {
            const size_t xbase = (((size_t)t * 2 + c) * 128 + r) * 384 + tid;
            xpi = __half2float(xg[xbase + 0 * 96]);
            xpf = __half2float(xg[xbase + 1 * 96]);
            xpg = __half2float(xg[xbase + 2 * 96]);
            xpo = __half2float(xg[xbase + 3 * 96]);
        }

        if (t == 0) {
            for (int i = tid; i < 384; i += 512) G[i] = 0.f;  // h_prev = 0
            __syncthreads();
        } else {
            // ---- wait: all 128 WGs of this domain finished step t-1 ----
            if (tid < 128) {
                while (__hip_atomic_load(&myflags[tid * FPAD], __ATOMIC_RELAXED,
                                         __HIP_MEMORY_SCOPE_AGENT) < (unsigned)t) {
                    __builtin_amdgcn_s_sleep(2);   // backoff: cut L3 poll traffic
                }
            }
            __syncthreads();

            // ---- stage h_prev[b0..b0+16][:] into LDS: 6 x dwordx4 sc0 sc1
            //      coherence-bypass loads per thread (16B-aligned; every
            //      dword was drained before the producer's flag) ----
            f32x4 hv6[6];
#pragma unroll
            for (int i = 0; i < 6; ++i) {
                const int g = i * 512 + tid;        // 0..3071
                const int b = g / 192;
                const int k = (g - b * 192) * 4;
                const float* src = &out[((size_t)(b0 + b) * T_LEN + (t - 1)) * H_SZ + k];
                asm volatile("global_load_dwordx4 %0, %1, off sc0 sc1"
                             : "=v"(hv6[i]) : "v"(src));
            }
            asm volatile("s_waitcnt vmcnt(0)" ::: "memory");
            __builtin_amdgcn_sched_barrier(0);   // rule #18: no early hv6 use
#pragma unroll
            for (int i = 0; i < 6; ++i) {
                const int g = i * 512 + tid;
                const int b = g / 192;
                const int k = (g - b * 192) * 4;
                *(f32x4*)&hsl[b * H_SZ + k] = hv6[i];
            }
            __syncthreads();

            // ---- dot: acc[6 rows][4 batches] over 24-element K segment ----
            float acc[6][4];
#pragma unroll
            for (int a = 0; a < 6; ++a)
#pragma unroll
                for (int q = 0; q < 4; ++q) acc[a][q] = 0.f;

            for (int jj = 0; jj < 6; ++jj) {
                const int k = ks * 4 + jj * 128;   // lanes stride-1 in k
                float4 hv[4];
#pragma unroll
                for (int q = 0; q < 4; ++q)
                    hv[q] = *(const float4*)&hsl[(tb + q) * H_SZ + k];
#pragma unroll
                for (int a = 0; a < 6; ++a) {
                    const float4 wv = *(const float4*)&Wsl[(tr + a) * H_SZ + k];
#pragma unroll
                    for (int q = 0; q < 4; ++q) {
                        acc[a][q] = fmaf(wv.x, hv[q].x, acc[a][q]);
                        acc[a][q] = fmaf(wv.y, hv[q].y, acc[a][q]);
                        acc[a][q] = fmaf(wv.z, hv[q].z, acc[a][q]);
                        acc[a][q] = fmaf(wv.w, hv[q].w, acc[a][q]);
                    }
                }
            }
            __syncthreads();                 // hsl reads done -> reuse as P

            // ---- write partials P[out 0..383][ks 0..31] ----
            float* P = hsl;
#pragma unroll
            for (int a = 0; a < 6; ++a)
#pragma unroll
                for (int q = 0; q < 4; ++q)
                    P[((tr + a) * 16 + (tb + q)) * 32 + ks] = acc[a][q];
            __syncthreads();

            // ---- reduce (diagonal reads: bank-conflict-free) ----
            if (tid < 384) {
                const int oi = tid;
                float s = 0.f;
#pragma unroll
                for (int kk = 0; kk < 32; ++kk) {
                    const int k2 = (kk + oi) & 31;
                    s += P[oi * 32 + k2];
                }
                G[oi] = s;
            }
            __syncthreads();
        }

        // ---- gate combine: threads 0..95, one (unit, batch) each ----
        if (tid < 96) {
            const float pi = G[(0 * 6 + cj) * 16 + cb] + xpi;
            const float pf = G[(1 * 6 + cj) * 16 + cb] + xpf;
            const float pg = G[(2 * 6 + cj) * 16 + cb] + xpg;
            const float po = G[(3 * 6 + cj) * 16 + cb] + xpo;
            const float ig = 1.f / (1.f + __expf(-pi));
            const float fg = 1.f / (1.f + __expf(-pf));
            const float gg = fast_tanh(pg);
            const float og = 1.f / (1.f + __expf(-po));
            c_reg = fg * c_reg + ig * gg;
            const float h = og * fast_tanh(c_reg);
            // write-through to the device coherence point; readers bypass too
            __hip_atomic_store(&out[((size_t)(b0 + cb) * T_LEN + t) * H_SZ + u0 + cj],
                               h, __ATOMIC_RELAXED, __HIP_MEMORY_SCOPE_AGENT);
        }
        // drain only vmem stores, then barrier so ALL waves' stores are done
        asm volatile("s_waitcnt vmcnt(0)" ::: "memory");
        __syncthreads();

        // ---- publish: one relaxed flag store (flag = steps completed) ----
        if (tid == 0) {
            __hip_atomic_store(&myflags[r * FPAD], (unsigned)(t + 1),
                               __ATOMIC_RELAXED, __HIP_MEMORY_SCOPE_AGENT);
        }
    }
}

// ---------------------------------------------------------------------------
extern "C" void kernel_launch(void* const* d_in, const int* in_sizes, int n_in,
                              void* d_out, int out_size, void* d_ws, size_t ws_size,
                              hipStream_t stream)
{
    (void)in_sizes; (void)n_in; (void)out_size; (void)ws_size;
    const float* hidden = (const float*)d_in[0];
    const float* W_ih   = (const float*)d_in[1];
    const float* W_hh   = (const float*)d_in[2];
    const float* b_ih   = (const float*)d_in[3];
    const float* b_hh   = (const float*)d_in[4];
    float* out = (float*)d_out;

    __half* xg = (__half*)d_ws;                                  // 201,326,592 B
    unsigned* flags = (unsigned*)((char*)d_ws +
                      (size_t)T_LEN * B_SZ * G4 * sizeof(__half)); // 8192 u32

    zero_cnt<<<dim3(8), dim3(1024), 0, stream>>>(flags);
    xg_gemm<<<dim3(G4 / 128, (B_SZ * T_LEN) / 128), dim3(256), 0, stream>>>(
        hidden, W_ih, b_ih, b_hh, xg);

    const int smem = (24 * H_SZ + 12288 + 384) * (int)sizeof(float);  // 124,416 B
    (void)hipFuncSetAttribute((const void*)lstm_rec,
                              hipFuncAttributeMaxDynamicSharedMemorySize, smem);
    void* args[] = { (void*)&xg, (void*)&W_hh, (void*)&out, (void*)&flags };
    (void)hipLaunchCooperativeKernel((void*)lstm_rec, dim3(256), dim3(512),
                                     args, (unsigned)smem, stream);
}

// Round 7
// 5068.766 us; speedup vs baseline: 1.6087x; 1.1199x over previous
//
#include <hip/hip_runtime.h>
#include <hip/hip_fp16.h>

#define T_LEN 1024
#define B_SZ  32
#define D_IN  768
#define H_SZ  768
#define G4    3072   // 4*H
#define FPAD  32     // flag padding: 1 flag per 128-byte line
#define LDA   40     // xg_gemm: padded LDS row stride (bf16) for 32-wide K tiles
#define HPAD  776    // lstm_rec: padded row stride (bf16): uniform 8-way b128 = floor

typedef __attribute__((ext_vector_type(8))) short short8;   // 8 bf16 (4 VGPRs)
typedef __attribute__((ext_vector_type(4))) float f32x4;    // MFMA frag / 16B
typedef __attribute__((ext_vector_type(4))) unsigned u32x4; // asm-friendly 16B

// ---------------------------------------------------------------------------
// Packed-h exchange: producer-side bf16 hi/lo split. [domain c][parity][b][k]
// as u16. 384 KB total -> L3-resident. Written by combine threads with
// global_store_short sc0 sc1; read by stage with dwordx4 sc0 sc1. Parity
// reuse is safe by the transitive flag argument (flag t+1 => that WG finished
// its step-t stage reads of the t-1 slot).
// ---------------------------------------------------------------------------
__device__ unsigned short xch_hi[2 * 2 * 16 * 768];
__device__ unsigned short xch_lo[2 * 2 * 16 * 768];

// bitwise fp32 -> bf16 hi/lo split (exact residual; 3-term MFMA error ~2^-16 rel)
__device__ __forceinline__ void split2(float x0, float x1, unsigned& hp, unsigned& lp)
{
    const unsigned u0 = __float_as_uint(x0);
    const unsigned u1 = __float_as_uint(x1);
    const unsigned h0 = u0 & 0xffff0000u, h1 = u1 & 0xffff0000u;
    hp = (h0 >> 16) | h1;
    const float l0 = x0 - __uint_as_float(h0);
    const float l1 = x1 - __uint_as_float(h1);
    lp = (__float_as_uint(l0) >> 16) | (__float_as_uint(l1) & 0xffff0000u);
}

// ---------------------------------------------------------------------------
// Phase A: split-bf16 3-term MFMA GEMM (verified R1/R2: ~0.36 ms). Epilogue
// writes xg in consumer-dense layout xg[t][c][r][gate][cb][cj] (verified R5:
// FETCH 664->370 MB). Unchanged.
// ---------------------------------------------------------------------------
__global__ __launch_bounds__(256, 2)
void xg_gemm(const float* __restrict__ hidden, const float* __restrict__ W_ih,
             const float* __restrict__ b_ih, const float* __restrict__ b_hh,
             __half* __restrict__ xg)
{
    __shared__ unsigned short Ah[128 * LDA];
    __shared__ unsigned short Al[128 * LDA];
    __shared__ unsigned short Bh[128 * LDA];
    __shared__ unsigned short Bl[128 * LDA];

    const int tid = threadIdx.x;
    const int n0 = blockIdx.x * 128;
    const int m0 = blockIdx.y * 128;

    const int srow = tid >> 1;
    const int skh  = (tid & 1) * 16;
    const int m = m0 + srow;
    const float* arow = hidden + ((size_t)(m & 31) * T_LEN + (m >> 5)) * D_IN;
    const float* brow = W_ih + (size_t)(n0 + srow) * D_IN;

    const int lane = tid & 63;
    const int wid  = tid >> 6;
    const int wm = (wid >> 1) * 64;
    const int wn = (wid & 1) * 64;
    const int fr = lane & 15;
    const int fk = (lane >> 4) * 8;

    f32x4 acc[4][4];
#pragma unroll
    for (int i = 0; i < 4; ++i)
#pragma unroll
        for (int j = 0; j < 4; ++j) acc[i][j] = (f32x4)0.f;

    float4 av[4], bv[4];
#pragma unroll
    for (int q = 0; q < 4; ++q) {
        av[q] = *(const float4*)(arow + skh + 4 * q);
        bv[q] = *(const float4*)(brow + skh + 4 * q);
    }

    for (int kb = 0; kb < D_IN; kb += 32) {
        __syncthreads();
        {
            const float* f = (const float*)av;
            unsigned hp[8], lp[8];
#pragma unroll
            for (int p = 0; p < 8; ++p) split2(f[2 * p], f[2 * p + 1], hp[p], lp[p]);
            *(uint4*)&Ah[srow * LDA + skh]     = make_uint4(hp[0], hp[1], hp[2], hp[3]);
            *(uint4*)&Ah[srow * LDA + skh + 8] = make_uint4(hp[4], hp[5], hp[6], hp[7]);
            *(uint4*)&Al[srow * LDA + skh]     = make_uint4(lp[0], lp[1], lp[2], lp[3]);
            *(uint4*)&Al[srow * LDA + skh + 8] = make_uint4(lp[4], lp[5], lp[6], lp[7]);
        }
        {
            const float* f = (const float*)bv;
            unsigned hp[8], lp[8];
#pragma unroll
            for (int p = 0; p < 8; ++p) split2(f[2 * p], f[2 * p + 1], hp[p], lp[p]);
            *(uint4*)&Bh[srow * LDA + skh]     = make_uint4(hp[0], hp[1], hp[2], hp[3]);
            *(uint4*)&Bh[srow * LDA + skh + 8] = make_uint4(hp[4], hp[5], hp[6], hp[7]);
            *(uint4*)&Bl[srow * LDA + skh]     = make_uint4(lp[0], lp[1], lp[2], lp[3]);
            *(uint4*)&Bl[srow * LDA + skh + 8] = make_uint4(lp[4], lp[5], lp[6], lp[7]);
        }
        __syncthreads();

        if (kb + 32 < D_IN) {
#pragma unroll
            for (int q = 0; q < 4; ++q) {
                av[q] = *(const float4*)(arow + kb + 32 + skh + 4 * q);
                bv[q] = *(const float4*)(brow + kb + 32 + skh + 4 * q);
            }
        }

        short8 afh[4], afl[4], bfh[4], bfl[4];
#pragma unroll
        for (int i = 0; i < 4; ++i) {
            afh[i] = *(const short8*)&Ah[(wm + i * 16 + fr) * LDA + fk];
            afl[i] = *(const short8*)&Al[(wm + i * 16 + fr) * LDA + fk];
            bfh[i] = *(const short8*)&Bh[(wn + i * 16 + fr) * LDA + fk];
            bfl[i] = *(const short8*)&Bl[(wn + i * 16 + fr) * LDA + fk];
        }
#pragma unroll
        for (int i = 0; i < 4; ++i)
#pragma unroll
            for (int j = 0; j < 4; ++j) {
                acc[i][j] = __builtin_amdgcn_mfma_f32_16x16x32_bf16(afh[i], bfh[j], acc[i][j], 0, 0, 0);
                acc[i][j] = __builtin_amdgcn_mfma_f32_16x16x32_bf16(afh[i], bfl[j], acc[i][j], 0, 0, 0);
                acc[i][j] = __builtin_amdgcn_mfma_f32_16x16x32_bf16(afl[i], bfh[j], acc[i][j], 0, 0, 0);
            }
    }

    const int rbase = (lane >> 4) * 4;
#pragma unroll
    for (int j = 0; j < 4; ++j) {
        const int gg = n0 + wn + j * 16 + fr;       // global gate-column
        const int gate = gg / 768;
        const int u    = gg - gate * 768;
        const int rq   = u / 6;
        const int cj   = u - rq * 6;
        const float bias = b_ih[gg] + b_hh[gg];
        const size_t cbase = (size_t)rq * 384 + gate * 96 + cj;
#pragma unroll
        for (int i = 0; i < 4; ++i) {
#pragma unroll
            for (int rx = 0; rx < 4; ++rx) {
                const int mm = m0 + wm + i * 16 + rbase + rx;
                const int t = mm >> 5, b = mm & 31;
                const size_t addr = (((size_t)t * 2 + (b >> 4)) * 128) * 384
                                    + cbase + (b & 15) * 6;
                xg[addr] = __float2half_rn(acc[i][j][rx] + bias);
            }
        }
    }
}

// ---------------------------------------------------------------------------
__global__ void zero_cnt(unsigned* flags) {
    flags[blockIdx.x * 1024 + threadIdx.x] = 0u;
}

// fast tanh via v_exp_f32; ~1e-7 abs error, no overflow (e<=1).
__device__ __forceinline__ float fast_tanh(float x) {
    const float e = __expf(-2.f * fabsf(x));
    const float r = __fdividef(1.f - e, 1.f + e);
    return copysignf(r, x);
}

// ---------------------------------------------------------------------------
// Phase B: persistent cooperative recurrence, 512 threads. R7: recurrent dot
// via split-bf16 3-term MFMA (R2-verified fragment layout) with PRODUCER-side
// hi/lo split through the xch_hi/xch_lo exchange:
//  - stage (per thread): 6 coalesced dwordx4 sc0 sc1 loads + 6 uint4 LDS
//    writes, ZERO unpack VALU (loaded words ARE the Hh/Hl rows)
//  - dot: 8-way K-split (96 each), 18 MFMA/wave (2 row tiles x 3 ksteps x
//    3 terms), ~500 cyc wall vs scalar 2304
//  - reduce: 8-way through wave-major rbuf (conflict-free), 384 threads
//  - protocol (flags, poll+sleep, vmcnt drain, publish): R1/R6-identical
// ---------------------------------------------------------------------------
__global__ void __launch_bounds__(512, 1)
lstm_rec(const __half* __restrict__ xg, const float* __restrict__ Whh,
         float* __restrict__ out, unsigned* __restrict__ flags)
{
    extern __shared__ char smc[];
    unsigned short* Wh_s = (unsigned short*)smc;                 // 24*776*2 = 37248
    unsigned short* Wl_s = (unsigned short*)(smc + 37248);       // 37248
    unsigned short* Hh_s = (unsigned short*)(smc + 74496);       // 16*776*2 = 24832
    unsigned short* Hl_s = (unsigned short*)(smc + 99328);       // 24832
    float*          rbuf = (float*)(smc + 124160);               // 8*512*4 = 16384
    float*          G    = (float*)(smc + 140544);               // 384*4 -> 142080

    const int tid = threadIdx.x;             // 0..511
    const int wg  = blockIdx.x;
    const int c   = wg & 1;        // batch group (sync domain)
    const int r   = wg >> 1;       // unit group 0..127
    const int u0  = r * 6;
    const int b0  = c * 16;

    // ---- load + split W_hh slice once: rows (gate*768 + u0 + j) ----
    for (int i = tid; i < 24 * 192; i += 512) {
        const int rr2 = i / 192;             // local row 0..23
        const int kc = (i % 192) * 4;
        const int gate = rr2 / 6, j = rr2 % 6;
        const float4 v = *(const float4*)&Whh[(size_t)(gate * H_SZ + u0 + j) * H_SZ + kc];
        unsigned h01, l01, h23, l23;
        split2(v.x, v.y, h01, l01);
        split2(v.z, v.w, h23, l23);
        *(uint2*)&Wh_s[rr2 * HPAD + kc] = make_uint2(h01, h23);
        *(uint2*)&Wl_s[rr2 * HPAD + kc] = make_uint2(l01, l23);
    }

    // MFMA roles (R2-verified layout)
    const int lane = tid & 63;
    const int wv   = tid >> 6;               // wave = K-eighth owner
    const int fr   = lane & 15;              // frag row (W) / batch row (h)
    const int fkb  = (lane >> 4) * 8;        // frag k offset
    const int rb4  = (lane >> 4) * 4;        // D frag row base
    // stage role: one batch row, 24 consecutive k per thread
    const int sb   = tid >> 5;               // batch 0..15
    const int sk0  = (tid & 31) * 24;        // k base

    // combine-phase role (threads 0..95)
    const int cj = tid % 6;                  // unit within group
    const int cb = tid / 6;                  // batch within group
    float c_reg = 0.f;                       // cell state, register-resident

    unsigned* myflags = flags + c * 128 * FPAD;

    __builtin_amdgcn_fence(__ATOMIC_ACQUIRE, "agent");  // once: clear poison
    __syncthreads();

    for (int t = 0; t < T_LEN; ++t) {
        // ---- prefetch xg[t]: consumer-dense, 4 x 192-B coalesced runs ----
        float xpi = 0.f, xpf = 0.f, xpg = 0.f, xpo = 0.f;
        if (tid < 96) {
            const size_t xbase = (((size_t)t * 2 + c) * 128 + r) * 384 + tid;
            xpi = __half2float(xg[xbase + 0 * 96]);
            xpf = __half2float(xg[xbase + 1 * 96]);
            xpg = __half2float(xg[xbase + 2 * 96]);
            xpo = __half2float(xg[xbase + 3 * 96]);
        }

        if (t == 0) {
            for (int i = tid; i < 384; i += 512) G[i] = 0.f;  // h_prev = 0
            __syncthreads();
        } else {
            // ---- wait: all 128 WGs of this domain finished step t-1 ----
            if (tid < 128) {
                while (__hip_atomic_load(&myflags[tid * FPAD], __ATOMIC_RELAXED,
                                         __HIP_MEMORY_SCOPE_AGENT) < (unsigned)t) {
                    __builtin_amdgcn_s_sleep(2);   // backoff: cut L3 poll traffic
                }
            }
            __syncthreads();

            // ---- stage packed h: 6 dwordx4 sc0 sc1 loads -> 6 uint4 LDS
            //      writes; zero unpack (words ARE the Hh/Hl rows) ----
            {
                const size_t xb = ((size_t)(c * 2 + ((t - 1) & 1)) * 16 + sb) * 768 + sk0;
                u32x4 h0, h1, h2, l0, l1, l2;
                asm volatile("global_load_dwordx4 %0, %1, off sc0 sc1"
                             : "=v"(h0) : "v"(&xch_hi[xb]));
                asm volatile("global_load_dwordx4 %0, %1, off sc0 sc1"
                             : "=v"(h1) : "v"(&xch_hi[xb + 8]));
                asm volatile("global_load_dwordx4 %0, %1, off sc0 sc1"
                             : "=v"(h2) : "v"(&xch_hi[xb + 16]));
                asm volatile("global_load_dwordx4 %0, %1, off sc0 sc1"
                             : "=v"(l0) : "v"(&xch_lo[xb]));
                asm volatile("global_load_dwordx4 %0, %1, off sc0 sc1"
                             : "=v"(l1) : "v"(&xch_lo[xb + 8]));
                asm volatile("global_load_dwordx4 %0, %1, off sc0 sc1"
                             : "=v"(l2) : "v"(&xch_lo[xb + 16]));
                asm volatile("s_waitcnt vmcnt(0)" ::: "memory");
                __builtin_amdgcn_sched_barrier(0);   // rule #18: no early use
                *(u32x4*)&Hh_s[sb * HPAD + sk0]      = h0;
                *(u32x4*)&Hh_s[sb * HPAD + sk0 + 8]  = h1;
                *(u32x4*)&Hh_s[sb * HPAD + sk0 + 16] = h2;
                *(u32x4*)&Hl_s[sb * HPAD + sk0]      = l0;
                *(u32x4*)&Hl_s[sb * HPAD + sk0 + 8]  = l1;
                *(u32x4*)&Hl_s[sb * HPAD + sk0 + 16] = l2;
            }
            __syncthreads();

            // ---- dot via MFMA: wave wv owns k in [96*wv, 96*wv+96) ----
            f32x4 acc0 = (f32x4)0.f, acc1 = (f32x4)0.f;
            const int kwb = wv * 96;
#pragma unroll
            for (int ksd = 0; ksd < 3; ++ksd) {
                const int ko = kwb + ksd * 32 + fkb;
                const short8 bh  = *(const short8*)&Hh_s[fr * HPAD + ko];
                const short8 bl  = *(const short8*)&Hl_s[fr * HPAD + ko];
                const short8 a0h = *(const short8*)&Wh_s[fr * HPAD + ko];
                const short8 a0l = *(const short8*)&Wl_s[fr * HPAD + ko];
                const short8 a1h = *(const short8*)&Wh_s[(8 + fr) * HPAD + ko];
                const short8 a1l = *(const short8*)&Wl_s[(8 + fr) * HPAD + ko];
                acc0 = __builtin_amdgcn_mfma_f32_16x16x32_bf16(a0h, bh, acc0, 0, 0, 0);
                acc0 = __builtin_amdgcn_mfma_f32_16x16x32_bf16(a0h, bl, acc0, 0, 0, 0);
                acc0 = __builtin_amdgcn_mfma_f32_16x16x32_bf16(a0l, bh, acc0, 0, 0, 0);
                acc1 = __builtin_amdgcn_mfma_f32_16x16x32_bf16(a1h, bh, acc1, 0, 0, 0);
                acc1 = __builtin_amdgcn_mfma_f32_16x16x32_bf16(a1h, bl, acc1, 0, 0, 0);
                acc1 = __builtin_amdgcn_mfma_f32_16x16x32_bf16(a1l, bh, acc1, 0, 0, 0);
            }

            // ---- stash partials (wave-major rbuf: conflict-free) ----
#pragma unroll
            for (int rix = 0; rix < 4; ++rix) {
                rbuf[wv * 512 + (rb4 + rix) * 16 + fr]        = acc0[rix];
                rbuf[wv * 512 + (16 + rb4 + rix) * 16 + fr]   = acc1[rix];
            }
            __syncthreads();

            // ---- 8-way cross-wave K-reduce -> G[24][16] ----
            if (tid < 384) {
                const int row = tid >> 4, colr = tid & 15;
                const int idx = (row < 16) ? tid : ((row + 8) * 16 + colr);
                float s = 0.f;
#pragma unroll
                for (int w = 0; w < 8; ++w) s += rbuf[w * 512 + idx];
                G[tid] = s;
            }
            __syncthreads();
        }

        // ---- gate combine: threads 0..95, one (unit, batch) each ----
        if (tid < 96) {
            const float pi = G[(0 * 6 + cj) * 16 + cb] + xpi;
            const float pf = G[(1 * 6 + cj) * 16 + cb] + xpf;
            const float pg = G[(2 * 6 + cj) * 16 + cb] + xpg;
            const float po = G[(3 * 6 + cj) * 16 + cb] + xpo;
            const float ig = 1.f / (1.f + __expf(-pi));
            const float fg = 1.f / (1.f + __expf(-pf));
            const float gg = fast_tanh(pg);
            const float og = 1.f / (1.f + __expf(-po));
            c_reg = fg * c_reg + ig * gg;
            const float h = og * fast_tanh(c_reg);
            // output: plain cached store (only read after kernel end)
            out[((size_t)(b0 + cb) * T_LEN + t) * H_SZ + u0 + cj] = h;
            // producer-side split: publish bf16 hi/lo shorts (same trunc
            // split the MFMA consumed in R2 -> identical numerics)
            const unsigned ub = __float_as_uint(h);
            const unsigned uh = ub & 0xffff0000u;
            const float lo = h - __uint_as_float(uh);
            const unsigned hs = ub >> 16;
            const unsigned ls = __float_as_uint(lo) >> 16;
            const size_t pb = ((size_t)(c * 2 + (t & 1)) * 16 + cb) * 768 + u0 + cj;
            asm volatile("global_store_short %0, %1, off sc0 sc1"
                         :: "v"(&xch_hi[pb]), "v"(hs) : "memory");
            asm volatile("global_store_short %0, %1, off sc0 sc1"
                         :: "v"(&xch_lo[pb]), "v"(ls) : "memory");
        }
        // drain vmem stores, then barrier so ALL waves' stores are done
        asm volatile("s_waitcnt vmcnt(0)" ::: "memory");
        __syncthreads();

        // ---- publish: one relaxed flag store (flag = steps completed) ----
        if (tid == 0) {
            __hip_atomic_store(&myflags[r * FPAD], (unsigned)(t + 1),
                               __ATOMIC_RELAXED, __HIP_MEMORY_SCOPE_AGENT);
        }
    }
}

// ---------------------------------------------------------------------------
extern "C" void kernel_launch(void* const* d_in, const int* in_sizes, int n_in,
                              void* d_out, int out_size, void* d_ws, size_t ws_size,
                              hipStream_t stream)
{
    (void)in_sizes; (void)n_in; (void)out_size; (void)ws_size;
    const float* hidden = (const float*)d_in[0];
    const float* W_ih   = (const float*)d_in[1];
    const float* W_hh   = (const float*)d_in[2];
    const float* b_ih   = (const float*)d_in[3];
    const float* b_hh   = (const float*)d_in[4];
    float* out = (float*)d_out;

    __half* xg = (__half*)d_ws;                                  // 201,326,592 B
    unsigned* flags = (unsigned*)((char*)d_ws +
                      (size_t)T_LEN * B_SZ * G4 * sizeof(__half)); // 8192 u32

    zero_cnt<<<dim3(8), dim3(1024), 0, stream>>>(flags);
    xg_gemm<<<dim3(G4 / 128, (B_SZ * T_LEN) / 128), dim3(256), 0, stream>>>(
        hidden, W_ih, b_ih, b_hh, xg);

    const int smem = 142080;  // W 74496 + H 49664 + rbuf 16384 + G 1536
    (void)hipFuncSetAttribute((const void*)lstm_rec,
                              hipFuncAttributeMaxDynamicSharedMemorySize, smem);
    void* args[] = { (void*)&xg, (void*)&W_hh, (void*)&out, (void*)&flags };
    (void)hipLaunchCooperativeKernel((void*)lstm_rec, dim3(256), dim3(512),
                                     args, (unsigned)smem, stream);
}